// Round 5
// baseline (389.993 us; speedup 1.0000x reference)
//
#include <hip/hip_runtime.h>
#include <hip/hip_bf16.h>

#define N_NODES 50000
#define N_EDGES 800000
#define IN_CH 128
#define HID 256
#define PROJ 128
#define N_GRAPHS 512

typedef short bf16x8 __attribute__((ext_vector_type(8)));
typedef float f32x4 __attribute__((ext_vector_type(4)));

__device__ inline float bf2f(unsigned short u) {
  union { unsigned int i; float f; } x;
  x.i = ((unsigned int)u) << 16;
  return x.f;
}
__device__ inline unsigned short f2bf(float f) {
  __hip_bfloat16 h = __float2bfloat16(f);  // RNE
  return *reinterpret_cast<unsigned short*>(&h);
}

// ---------------------------------------------------------------------------
// CSR build
// ---------------------------------------------------------------------------
__global__ __launch_bounds__(256) void count_kernel(const int* __restrict__ dst,
                                                    int* __restrict__ cnt) {
  int e = blockIdx.x * 256 + threadIdx.x;
  if (e < N_EDGES) atomicAdd(&cnt[dst[e]], 1);
}

__global__ __launch_bounds__(256) void scan1_kernel(const int* __restrict__ cnt,
                                                    int* __restrict__ ptr,
                                                    int* __restrict__ bsum) {
  __shared__ int lds[256];
  const int tid = threadIdx.x;
  const int i = blockIdx.x * 256 + tid;
  int v = (i < N_NODES) ? cnt[i] : 0;
  lds[tid] = v;
  __syncthreads();
  for (int off = 1; off < 256; off <<= 1) {
    int t = (tid >= off) ? lds[tid - off] : 0;
    __syncthreads();
    lds[tid] += t;
    __syncthreads();
  }
  if (i < N_NODES) ptr[i] = lds[tid] - v;  // exclusive within block
  if (tid == 255) bsum[blockIdx.x] = lds[255];
}

__global__ __launch_bounds__(256) void scan2_kernel(const int* __restrict__ bsum,
                                                    int* __restrict__ boff,
                                                    int* __restrict__ ptr,
                                                    int nb) {
  __shared__ int lds[256];
  const int tid = threadIdx.x;
  int v = (tid < nb) ? bsum[tid] : 0;
  lds[tid] = v;
  __syncthreads();
  for (int off = 1; off < 256; off <<= 1) {
    int t = (tid >= off) ? lds[tid - off] : 0;
    __syncthreads();
    lds[tid] += t;
    __syncthreads();
  }
  if (tid < nb) boff[tid] = lds[tid] - v;
  if (tid == 255) ptr[N_NODES] = lds[255];
}

// adds block offsets AND writes the fill cursor (saves a d2d memcpy)
__global__ __launch_bounds__(256) void scan3_kernel(int* __restrict__ ptr,
                                                    const int* __restrict__ boff,
                                                    int* __restrict__ cursor) {
  int i = blockIdx.x * 256 + threadIdx.x;
  if (i < N_NODES) {
    int v = ptr[i] + boff[blockIdx.x];
    ptr[i] = v;
    cursor[i] = v;
  }
}

__global__ __launch_bounds__(256) void fill_kernel(const int* __restrict__ src,
                                                   const int* __restrict__ dst,
                                                   int* __restrict__ cursor,
                                                   int* __restrict__ esrc) {
  int e = blockIdx.x * 256 + threadIdx.x;
  if (e < N_EDGES) {
    int pos = atomicAdd(&cursor[dst[e]], 1);
    esrc[pos] = src[e];
  }
}

// ---------------------------------------------------------------------------
// Prep: x f32 -> bf16, W1/W2 [K][256] f32 -> transposed bf16 [256][K]
// ---------------------------------------------------------------------------
#define PREP_T1 (N_NODES * IN_CH / 4)
#define PREP_T2 (IN_CH * HID)
#define PREP_T3 (HID * HID)
__global__ __launch_bounds__(256) void prep_kernel(
    const float* __restrict__ x, const float* __restrict__ W1,
    const float* __restrict__ W2, __hip_bfloat16* __restrict__ xb,
    __hip_bfloat16* __restrict__ Wt1, __hip_bfloat16* __restrict__ Wt2) {
  int i = blockIdx.x * 256 + threadIdx.x;
  if (i < PREP_T1) {
    float4 v = reinterpret_cast<const float4*>(x)[i];
    ushort4 o = {f2bf(v.x), f2bf(v.y), f2bf(v.z), f2bf(v.w)};
    reinterpret_cast<ushort4*>(xb)[i] = o;
  } else if (i < PREP_T1 + PREP_T2) {
    int idx = i - PREP_T1;
    int k = idx / HID, n = idx % HID;
    Wt1[(size_t)n * IN_CH + k] = __float2bfloat16(W1[idx]);
  } else if (i < PREP_T1 + PREP_T2 + PREP_T3) {
    int idx = i - PREP_T1 - PREP_T2;
    int k = idx / HID, n = idx % HID;
    Wt2[(size_t)n * HID + k] = __float2bfloat16(W2[idx]);
  }
}

// ---------------------------------------------------------------------------
// Fused GIN layer: C[M][256] = relu( (feat + gather(feat)) @ W + bias )
//  - 256 threads = 4 waves; block tile BM=64 rows x all 256 cols.
//  - Phase 1: each wave gathers 16 rows (f32 accum, 4x-unrolled edge loop)
//    and writes bf16 rows into LDS A-panel with XOR chunk swizzle
//    (chunk c at position c ^ (row&7); chunk = 16 B).
//  - Phase 2: MFMA 16x16x32; A-frags from swizzled LDS, B-frags streamed
//    from global (Bt is 64-128 KB, L2-resident). Wave w owns cols w*64..+63.
// ---------------------------------------------------------------------------
template <int K, bool RELU>
__global__ __launch_bounds__(256) void fused_gin_kernel(
    const __hip_bfloat16* __restrict__ feat, const int* __restrict__ ptr,
    const int* __restrict__ esrc, const __hip_bfloat16* __restrict__ Bt,
    const float* __restrict__ bias, __hip_bfloat16* __restrict__ C, int M) {
  constexpr int BM = 64;
  constexpr int ROWB = K * 2;  // bytes per row
  __shared__ char ldsA[BM * ROWB];  // 16 KB (K=128) or 32 KB (K=256)
  const int tid = threadIdx.x;
  const int l = tid & 63;
  const int w = tid >> 6;  // 0..3
  const int row0 = blockIdx.x * BM;

  // ---- gather phase ----
  for (int i = 0; i < 16; ++i) {
    const int r = i * 4 + w;
    int node = row0 + r;
    if (node > M - 1) node = M - 1;
    const int beg = __builtin_amdgcn_readfirstlane(ptr[node]);
    const int end = __builtin_amdgcn_readfirstlane(ptr[node + 1]);
    if constexpr (K == 256) {
      const ushort4* u4 = reinterpret_cast<const ushort4*>(feat);
      ushort4 sv = u4[(size_t)node * 64 + l];
      float a0 = bf2f(sv.x), a1 = bf2f(sv.y), a2 = bf2f(sv.z), a3 = bf2f(sv.w);
      int e = beg;
      for (; e + 4 <= end; e += 4) {
        int s0 = esrc[e], s1 = esrc[e + 1], s2 = esrc[e + 2], s3 = esrc[e + 3];
        ushort4 v0 = u4[(size_t)s0 * 64 + l];
        ushort4 v1 = u4[(size_t)s1 * 64 + l];
        ushort4 v2 = u4[(size_t)s2 * 64 + l];
        ushort4 v3 = u4[(size_t)s3 * 64 + l];
        a0 += bf2f(v0.x) + bf2f(v1.x) + bf2f(v2.x) + bf2f(v3.x);
        a1 += bf2f(v0.y) + bf2f(v1.y) + bf2f(v2.y) + bf2f(v3.y);
        a2 += bf2f(v0.z) + bf2f(v1.z) + bf2f(v2.z) + bf2f(v3.z);
        a3 += bf2f(v0.w) + bf2f(v1.w) + bf2f(v2.w) + bf2f(v3.w);
      }
      for (; e < end; ++e) {
        int s = esrc[e];
        ushort4 v = u4[(size_t)s * 64 + l];
        a0 += bf2f(v.x); a1 += bf2f(v.y); a2 += bf2f(v.z); a3 += bf2f(v.w);
      }
      ushort4 o = {f2bf(a0), f2bf(a1), f2bf(a2), f2bf(a3)};
      const int c = l >> 1;               // 16B chunk 0..31
      const int cs = c ^ (r & 7);
      *reinterpret_cast<ushort4*>(ldsA + r * 512 + cs * 16 + (l & 1) * 8) = o;
    } else {
      const ushort2* u2 = reinterpret_cast<const ushort2*>(feat);
      ushort2 sv = u2[(size_t)node * 64 + l];
      float a0 = bf2f(sv.x), a1 = bf2f(sv.y);
      int e = beg;
      for (; e + 4 <= end; e += 4) {
        int s0 = esrc[e], s1 = esrc[e + 1], s2 = esrc[e + 2], s3 = esrc[e + 3];
        ushort2 v0 = u2[(size_t)s0 * 64 + l];
        ushort2 v1 = u2[(size_t)s1 * 64 + l];
        ushort2 v2 = u2[(size_t)s2 * 64 + l];
        ushort2 v3 = u2[(size_t)s3 * 64 + l];
        a0 += bf2f(v0.x) + bf2f(v1.x) + bf2f(v2.x) + bf2f(v3.x);
        a1 += bf2f(v0.y) + bf2f(v1.y) + bf2f(v2.y) + bf2f(v3.y);
      }
      for (; e < end; ++e) {
        int s = esrc[e];
        ushort2 v = u2[(size_t)s * 64 + l];
        a0 += bf2f(v.x); a1 += bf2f(v.y);
      }
      ushort2 o = {f2bf(a0), f2bf(a1)};
      const int c = l >> 2;               // 16B chunk 0..15
      const int cs = c ^ (r & 7);
      *reinterpret_cast<ushort2*>(ldsA + r * 256 + cs * 16 + (l & 3) * 4) = o;
    }
  }
  __syncthreads();

  // ---- MFMA phase ----
  f32x4 acc[4][4] = {};
  constexpr int NKS = K / 32;
#pragma unroll
  for (int ks = 0; ks < NKS; ++ks) {
    bf16x8 a[4], b[4];
    const int kc = ks * 4 + (l >> 4);  // chunk index within row
#pragma unroll
    for (int m = 0; m < 4; ++m) {
      int row = m * 16 + (l & 15);
      a[m] = *reinterpret_cast<const bf16x8*>(
          ldsA + row * ROWB + (kc ^ (row & 7)) * 16);
    }
#pragma unroll
    for (int n = 0; n < 4; ++n) {
      int col = w * 64 + n * 16 + (l & 15);
      b[n] = *reinterpret_cast<const bf16x8*>(
          reinterpret_cast<const char*>(Bt) +
          ((size_t)col * K + ks * 32 + (l >> 4) * 8) * 2);
    }
#pragma unroll
    for (int m = 0; m < 4; ++m)
#pragma unroll
      for (int n = 0; n < 4; ++n)
        acc[m][n] = __builtin_amdgcn_mfma_f32_16x16x32_bf16(a[m], b[n],
                                                            acc[m][n], 0, 0, 0);
  }

  // ---- epilogue: C/D layout col=lane&15, row=(lane>>4)*4+j ----
#pragma unroll
  for (int n = 0; n < 4; ++n) {
    int gc = w * 64 + n * 16 + (l & 15);
    float bv = bias[gc];
#pragma unroll
    for (int m = 0; m < 4; ++m) {
      int rbase = row0 + m * 16 + (l >> 4) * 4;
#pragma unroll
      for (int j = 0; j < 4; ++j) {
        int r = rbase + j;
        if (r < M) {
          float v = acc[m][n][j] + bv;
          if (RELU) v = fmaxf(v, 0.f);
          C[(size_t)r * 256 + gc] = __float2bfloat16(v);
        }
      }
    }
  }
}

// ---------------------------------------------------------------------------
// Mean-pool per graph (batch sorted). h bf16 -> hg f32. 4x unrolled.
// ---------------------------------------------------------------------------
__global__ __launch_bounds__(HID) void pool_kernel(
    const __hip_bfloat16* __restrict__ h, const int* __restrict__ batch,
    float* __restrict__ hgraph) {
  const int g = blockIdx.x;
  const int c = threadIdx.x;
  auto lower_bound = [&](int key) {
    int lo = 0, hi = N_NODES;
    while (lo < hi) {
      int mid = (lo + hi) >> 1;
      if (batch[mid] < key) lo = mid + 1; else hi = mid;
    }
    return lo;
  };
  const int s = lower_bound(g);
  const int e = lower_bound(g + 1);
  const unsigned short* hb = reinterpret_cast<const unsigned short*>(h);
  float a0 = 0.f, a1 = 0.f, a2 = 0.f, a3 = 0.f;
  int n = s;
  for (; n + 4 <= e; n += 4) {
    a0 += bf2f(hb[(size_t)(n + 0) * HID + c]);
    a1 += bf2f(hb[(size_t)(n + 1) * HID + c]);
    a2 += bf2f(hb[(size_t)(n + 2) * HID + c]);
    a3 += bf2f(hb[(size_t)(n + 3) * HID + c]);
  }
  for (; n < e; ++n) a0 += bf2f(hb[(size_t)n * HID + c]);
  float acc = (a0 + a1) + (a2 + a3);
  float cnt = fmaxf((float)(e - s), 1.0f);
  hgraph[g * HID + c] = acc / cnt;
}

// ---------------------------------------------------------------------------
// f32 row-block GEMM for the (tiny) projection head.
// ---------------------------------------------------------------------------
template <int K, int N, int R, bool RELU>
__global__ void gin_linear_kernel(const float* __restrict__ A,
                                  const float* __restrict__ W,
                                  const float* __restrict__ bias,
                                  float* __restrict__ Cout, int M) {
  __shared__ float As[R][K];
  const int row0 = blockIdx.x * R;
  const int tid = threadIdx.x;
  for (int idx = tid; idx < R * K; idx += N) {
    int r = idx / K, k = idx % K;
    int m = row0 + r;
    As[r][k] = (m < M) ? A[(size_t)m * K + k] : 0.f;
  }
  __syncthreads();
  float acc[R];
#pragma unroll
  for (int r = 0; r < R; ++r) acc[r] = bias[tid];
  for (int k = 0; k < K; ++k) {
    float w = W[k * N + tid];
#pragma unroll
    for (int r = 0; r < R; ++r) acc[r] = fmaf(As[r][k], w, acc[r]);
  }
#pragma unroll
  for (int r = 0; r < R; ++r) {
    int m = row0 + r;
    if (m < M) {
      float v = acc[r];
      if (RELU) v = fmaxf(v, 0.f);
      Cout[(size_t)m * N + tid] = v;
    }
  }
}

// ---------------------------------------------------------------------------
extern "C" void kernel_launch(void* const* d_in, const int* in_sizes, int n_in,
                              void* d_out, int out_size, void* d_ws,
                              size_t ws_size, hipStream_t stream) {
  const float* x = (const float*)d_in[0];
  const int* edge = (const int*)d_in[1];
  const int* batch = (const int*)d_in[2];
  const float* W1 = (const float*)d_in[3];
  const float* b1 = (const float*)d_in[4];
  const float* W2 = (const float*)d_in[5];
  const float* b2 = (const float*)d_in[6];
  const float* P1 = (const float*)d_in[7];
  const float* pb1 = (const float*)d_in[8];
  const float* P2 = (const float*)d_in[9];
  const float* pb2 = (const float*)d_in[10];
  const int* src = edge;
  const int* dst = edge + N_EDGES;

  char* ws = (char*)d_ws;
  size_t off = 0;
  auto alloc = [&](size_t bytes) {
    void* p = ws + off;
    off += (bytes + 255) & ~(size_t)255;
    return p;
  };
  __hip_bfloat16* xb  = (__hip_bfloat16*)alloc((size_t)N_NODES * IN_CH * 2);
  __hip_bfloat16* h1  = (__hip_bfloat16*)alloc((size_t)N_NODES * HID * 2);
  __hip_bfloat16* h2  = (__hip_bfloat16*)alloc((size_t)N_NODES * HID * 2);
  __hip_bfloat16* Wt1 = (__hip_bfloat16*)alloc((size_t)HID * IN_CH * 2);
  __hip_bfloat16* Wt2 = (__hip_bfloat16*)alloc((size_t)HID * HID * 2);
  float* hg = (float*)alloc((size_t)N_GRAPHS * HID * 4);
  float* t1 = (float*)alloc((size_t)N_GRAPHS * HID * 4);
  int* ptr = (int*)alloc((size_t)(N_NODES + 1) * 4);
  int* cursor = (int*)alloc((size_t)N_NODES * 4);
  int* esrc = (int*)alloc((size_t)N_EDGES * 4);
  int* bsum = (int*)alloc(256 * 4);
  int* boff = (int*)alloc(256 * 4);
  float* z = (float*)d_out;

  const int EB = (N_EDGES + 255) / 256;
  const int NB = (N_NODES + 255) / 256;  // 196

  // --- CSR build (dst-indexed) ---
  hipMemsetAsync(cursor, 0, (size_t)N_NODES * 4, stream);
  count_kernel<<<EB, 256, 0, stream>>>(dst, cursor);
  scan1_kernel<<<NB, 256, 0, stream>>>(cursor, ptr, bsum);
  scan2_kernel<<<1, 256, 0, stream>>>(bsum, boff, ptr, NB);
  scan3_kernel<<<NB, 256, 0, stream>>>(ptr, boff, cursor);
  fill_kernel<<<EB, 256, 0, stream>>>(src, dst, cursor, esrc);

  // --- prep (x->bf16, W1/W2 -> transposed bf16) ---
  prep_kernel<<<(PREP_T1 + PREP_T2 + PREP_T3 + 255) / 256, 256, 0, stream>>>(
      x, W1, W2, xb, Wt1, Wt2);

  // --- Layer 1 (fused gather + GEMM) ---
  fused_gin_kernel<IN_CH, true>
      <<<(N_NODES + 63) / 64, 256, 0, stream>>>(xb, ptr, esrc, Wt1, b1, h1, N_NODES);

  // --- Layer 2 (fused gather + GEMM) ---
  fused_gin_kernel<HID, true>
      <<<(N_NODES + 63) / 64, 256, 0, stream>>>(h1, ptr, esrc, Wt2, b2, h2, N_NODES);

  // --- Mean pool ---
  pool_kernel<<<N_GRAPHS, HID, 0, stream>>>(h2, batch, hg);

  // --- Projection head (f32, tiny) ---
  gin_linear_kernel<HID, HID, 8, true>
      <<<(N_GRAPHS + 7) / 8, HID, 0, stream>>>(hg, P1, pb1, t1, N_GRAPHS);
  gin_linear_kernel<HID, PROJ, 8, false>
      <<<(N_GRAPHS + 7) / 8, PROJ, 0, stream>>>(t1, P2, pb2, z, N_GRAPHS);
}